// Round 5
// baseline (222.250 us; speedup 1.0000x reference)
//
#include <hip/hip_runtime.h>
#include <hip/hip_bf16.h>

typedef __bf16 bf16x8 __attribute__((ext_vector_type(8)));
typedef float  f32x4  __attribute__((ext_vector_type(4)));
typedef int    i32x4  __attribute__((ext_vector_type(4)));

#define N_WORDS   8192
#define CHAR_LEN  16
#define WORD_DIM  300
#define CHAR_DIM  64
#define HID       128
#define G4        512      // 4*HID
#define INFO      556
#define KPAD      576      // 556 padded to 18*32
#define OUTD      512
#define WBL       32       // words per lstm block (2 M-tiles)
#define WB        16       // words per out block
#define L2E       1.4426950408889634f

// sigmoid: rcp(1+exp2(-x*log2e)) ; saturates correctly
__device__ __forceinline__ float sig_(float x) {
    return __builtin_amdgcn_rcpf(1.0f + __builtin_amdgcn_exp2f(-L2E * x));
}
// tanh: 1 - 2*rcp(1+exp2(2x*log2e)) ; correct at +-inf
__device__ __forceinline__ float tanh_(float x) {
    return 1.0f - 2.0f * __builtin_amdgcn_rcpf(1.0f + __builtin_amdgcn_exp2f((2.0f * L2E) * x));
}

// K0 fused: blocks [0,256): preT ; blocks [256,...): Wpad + WhhB conversion
// preT[dir][cid][j][tt] = (char_table[cid] . Wih[tt*128+j]) + bih + bhh  (fp32, gate-interleaved)
__global__ void prep_kernel(const float* __restrict__ char_table,
                            const float* __restrict__ Wih_f, const float* __restrict__ bih_f,
                            const float* __restrict__ bhh_f,
                            const float* __restrict__ Wih_b, const float* __restrict__ bih_b,
                            const float* __restrict__ bhh_b,
                            const float* __restrict__ W_out,
                            const float* __restrict__ Whh_f, const float* __restrict__ Whh_b,
                            float* __restrict__ preT,
                            __bf16* __restrict__ Wpad, __bf16* __restrict__ WhhB) {
    __shared__ float x[CHAR_DIM];
    if (blockIdx.x < 256) {
        const int dir = blockIdx.x & 1;
        const int cid = blockIdx.x >> 1;
        const float* Wih = dir ? Wih_b : Wih_f;
        const float* b1  = dir ? bih_b : bih_f;
        const float* b2  = dir ? bhh_b : bhh_f;
        if (threadIdx.x < CHAR_DIM) x[threadIdx.x] = char_table[cid * CHAR_DIM + threadIdx.x];
        __syncthreads();
        for (int g = threadIdx.x; g < G4; g += 256) {
            const f32x4* w4 = (const f32x4*)(Wih + g * CHAR_DIM);
            const f32x4* x4 = (const f32x4*)x;
            float s = b1[g] + b2[g];
            #pragma unroll
            for (int d = 0; d < CHAR_DIM / 4; ++d) {
                f32x4 wv = w4[d], xv = x4[d];
                s += wv[0]*xv[0] + wv[1]*xv[1] + wv[2]*xv[2] + wv[3]*xv[3];
            }
            int tt = g >> 7, j = g & (HID - 1);
            preT[(dir * 128 + cid) * G4 + j * 4 + tt] = s;
        }
    } else {
        int idx = (blockIdx.x - 256) * 256 + threadIdx.x;
        if (idx < OUTD * KPAD) {
            int row = idx / KPAD, col = idx - row * KPAD;
            Wpad[idx] = (col < INFO) ? (__bf16)W_out[row * INFO + col] : (__bf16)0.0f;
        } else {
            int j = idx - OUTD * KPAD;
            if (j < 2 * G4 * HID) {
                const float* src = (j < G4 * HID) ? Whh_f : Whh_b;
                int k = (j < G4 * HID) ? j : j - G4 * HID;
                WhhB[j] = (__bf16)src[k];
            }
        }
    }
}

// K2: persistent BiLSTM recurrence. Block: 32 words x 1 direction, 512 thr (8 waves).
// Wave w owns hidden cols [w*16, w*16+16) for all 4 gates; 2 M-tiles -> 32 MFMA/barrier.
__global__ __launch_bounds__(512, 2) void lstm_kernel(
        const int*   __restrict__ char_ids,   // [8192][16] int32
        const float* __restrict__ preT,       // [2][128][128][4] fp32 gate-interleaved
        const __bf16* __restrict__ WhhB,      // [2][512][128] bf16
        __bf16* __restrict__ char_feat) {     // [8192][256] bf16
    const int dir = blockIdx.y;
    const int wb  = blockIdx.x * WBL;
    const __bf16* Whh = WhhB + dir * G4 * HID;
    const float* preD = preT + dir * 128 * G4;

    const int tid  = threadIdx.x;
    const int wave = tid >> 6;
    const int lane = tid & 63;
    const int col  = lane & 15;
    const int quad = lane >> 4;
    const int jbase = wave * 16;

    __shared__ __bf16 h_lds[2][WBL][136];    // 272B row stride
    __shared__ int    cidT[CHAR_LEN][WBL];   // transposed, pre-multiplied byte offsets cid*8192

    {   // stage cid: tid covers 32 words x 16 t exactly
        int w = tid >> 4, t = tid & 15;
        cidT[t][w] = char_ids[(wb + w) * CHAR_LEN + t] * (G4 * 4);
    }
    for (int i = tid; i < 2 * WBL * 136; i += 512) ((__bf16*)h_lds)[i] = (__bf16)0.0f;

    // Hoist Whh B-fragments: B[k][n]=Whh[row=tt*128+jbase+col][k], k=ks*32+quad*8+j
    bf16x8 Bfrag[4][4];   // [gate][kstep] = 64 VGPRs
    #pragma unroll
    for (int tt = 0; tt < 4; ++tt) {
        int row = tt * HID + jbase + col;
        #pragma unroll
        for (int ks = 0; ks < 4; ++ks)
            Bfrag[tt][ks] = *(const bf16x8*)(Whh + row * HID + ks * 32 + quad * 8);
    }

    const char* base_lane = (const char*)(preD + (jbase + col) * 4);   // lane's gate-quad base

    float c[2][4] = {}, sumh[2][4] = {};

    __syncthreads();   // cidT + h zero-init visible

    // prefetch t=0 gather: per M-tile, 4 word-rows; one f32x4 = {i,f,g,o} per row
    f32x4 nx[2][4];
    {
        const int tc0 = dir ? (CHAR_LEN - 1) : 0;
        #pragma unroll
        for (int mt = 0; mt < 2; ++mt) {
            i32x4 off = *(const i32x4*)(&cidT[tc0][mt * 16 + quad * 4]);   // broadcast b128
            #pragma unroll
            for (int r = 0; r < 4; ++r)
                nx[mt][r] = *(const f32x4*)(base_lane + off[r]);
        }
    }

    for (int t = 0; t < CHAR_LEN; ++t) {
        const __bf16 (*hc)[136] = h_lds[t & 1];
        __bf16 (*hn)[136] = h_lds[(t + 1) & 1];

        // transpose nx[mt][r][tt] -> acc[mt][tt][r] (MFMA C register order)
        f32x4 acc[2][4];
        #pragma unroll
        for (int mt = 0; mt < 2; ++mt)
            #pragma unroll
            for (int tt = 0; tt < 4; ++tt)
                acc[mt][tt] = (f32x4){nx[mt][0][tt], nx[mt][1][tt], nx[mt][2][tt], nx[mt][3][tt]};

        {   // ks = 0
            bf16x8 A0 = *(const bf16x8*)(&hc[col][quad * 8]);
            bf16x8 A1 = *(const bf16x8*)(&hc[16 + col][quad * 8]);
            #pragma unroll
            for (int tt = 0; tt < 4; ++tt) {
                acc[0][tt] = __builtin_amdgcn_mfma_f32_16x16x32_bf16(A0, Bfrag[tt][0], acc[0][tt], 0, 0, 0);
                acc[1][tt] = __builtin_amdgcn_mfma_f32_16x16x32_bf16(A1, Bfrag[tt][0], acc[1][tt], 0, 0, 0);
            }
        }

        // prefetch next step's gather (depends only on cid; overlaps MFMA+epilogue)
        if (t + 1 < CHAR_LEN) {
            const int tc = dir ? (CHAR_LEN - 2 - t) : (t + 1);
            #pragma unroll
            for (int mt = 0; mt < 2; ++mt) {
                i32x4 off = *(const i32x4*)(&cidT[tc][mt * 16 + quad * 4]);
                #pragma unroll
                for (int r = 0; r < 4; ++r)
                    nx[mt][r] = *(const f32x4*)(base_lane + off[r]);
            }
        }

        #pragma unroll
        for (int ks = 1; ks < 4; ++ks) {
            bf16x8 A0 = *(const bf16x8*)(&hc[col][ks * 32 + quad * 8]);
            bf16x8 A1 = *(const bf16x8*)(&hc[16 + col][ks * 32 + quad * 8]);
            #pragma unroll
            for (int tt = 0; tt < 4; ++tt) {
                acc[0][tt] = __builtin_amdgcn_mfma_f32_16x16x32_bf16(A0, Bfrag[tt][ks], acc[0][tt], 0, 0, 0);
                acc[1][tt] = __builtin_amdgcn_mfma_f32_16x16x32_bf16(A1, Bfrag[tt][ks], acc[1][tt], 0, 0, 0);
            }
        }

        // gate order i,f,g,o ; C/D layout: word-row = quad*4+r, col = n
        #pragma unroll
        for (int mt = 0; mt < 2; ++mt)
            #pragma unroll
            for (int r = 0; r < 4; ++r) {
                float iv = sig_(acc[mt][0][r]);
                float fv = sig_(acc[mt][1][r]);
                float gv = tanh_(acc[mt][2][r]);
                float ov = sig_(acc[mt][3][r]);
                float cv = fv * c[mt][r] + iv * gv;
                c[mt][r] = cv;
                float hv = ov * tanh_(cv);
                sumh[mt][r] += hv;
                hn[mt * 16 + quad * 4 + r][jbase + col] = (__bf16)hv;
            }
        __syncthreads();
    }

    #pragma unroll
    for (int mt = 0; mt < 2; ++mt)
        #pragma unroll
        for (int r = 0; r < 4; ++r)
            char_feat[(wb + mt * 16 + quad * 4 + r) * 256 + dir * HID + jbase + col]
                = (__bf16)sumh[mt][r];
}

// K3: out[word][o] = tanh(feat . W_out[o] + b_out[o]); M=16 tile, MFMA over K=576
__global__ __launch_bounds__(256, 4) void out_kernel(
        const int*   __restrict__ word_ids,
        const float* __restrict__ word_table,   // [50000][300] fp32
        const __bf16* __restrict__ char_feat,   // [8192][256] bf16
        const __bf16* __restrict__ Wpad,        // [512][576] bf16
        const float* __restrict__ b_out,        // [512] fp32
        float* __restrict__ out) {              // [8192][512] fp32
    const int wb  = blockIdx.x * WB;
    const int tid = threadIdx.x;
    const int wave = tid >> 6, lane = tid & 63, col = lane & 15, quad = lane >> 4;

    __shared__ __bf16 feat[WB][584];   // 1168B row stride, 16B aligned
    __shared__ int wid[WB];
    if (tid < WB) wid[tid] = word_ids[wb + tid];
    __syncthreads();
    // word part: 300 = 75 f32x4 chunks per row (rows are 1200B -> 16B aligned)
    for (int idx = tid; idx < WB * 75; idx += 256) {
        int row = idx / 75, ch = idx - row * 75;
        f32x4 v = *(const f32x4*)(word_table + wid[row] * WORD_DIM + ch * 4);
        __bf16* d = &feat[row][ch * 4];
        d[0] = (__bf16)v[0]; d[1] = (__bf16)v[1]; d[2] = (__bf16)v[2]; d[3] = (__bf16)v[3];
    }
    // char part: 256 bf16 = 32 bf16x8 chunks per row
    for (int idx = tid; idx < WB * 32; idx += 256) {
        int row = idx / 32, ch = idx - row * 32;
        bf16x8 v = *(const bf16x8*)(char_feat + (wb + row) * 256 + ch * 8);
        __bf16* d = &feat[row][WORD_DIM + ch * 8];
        #pragma unroll
        for (int e = 0; e < 8; ++e) d[e] = v[e];
    }
    // zero pad 556..583
    for (int idx = tid; idx < WB * 28; idx += 256) {
        int row = idx / 28, cc = idx - row * 28;
        feat[row][INFO + cc] = (__bf16)0.0f;
    }
    __syncthreads();

    f32x4 acc[8];
    #pragma unroll
    for (int nt = 0; nt < 8; ++nt) acc[nt] = (f32x4){0.f, 0.f, 0.f, 0.f};

    #pragma unroll 2
    for (int kb = 0; kb < KPAD / 32; ++kb) {
        bf16x8 A = *(const bf16x8*)(&feat[col][kb * 32 + quad * 8]);
        #pragma unroll
        for (int nt = 0; nt < 8; ++nt) {
            int n = wave * 128 + nt * 16 + col;
            bf16x8 B = *(const bf16x8*)(Wpad + n * KPAD + kb * 32 + quad * 8);
            acc[nt] = __builtin_amdgcn_mfma_f32_16x16x32_bf16(A, B, acc[nt], 0, 0, 0);
        }
    }

    #pragma unroll
    for (int nt = 0; nt < 8; ++nt) {
        int n = wave * 128 + nt * 16 + col;
        float bo = b_out[n];
        #pragma unroll
        for (int r = 0; r < 4; ++r) {
            int word = wb + quad * 4 + r;
            out[word * OUTD + n] = tanh_(acc[nt][r] + bo);
        }
    }
}

extern "C" void kernel_launch(void* const* d_in, const int* in_sizes, int n_in,
                              void* d_out, int out_size, void* d_ws, size_t ws_size,
                              hipStream_t stream) {
    const int*   word_ids   = (const int*)d_in[0];
    const int*   char_ids   = (const int*)d_in[1];
    const float* word_table = (const float*)d_in[2];
    const float* char_table = (const float*)d_in[3];
    const float* Wih_f = (const float*)d_in[4];
    const float* Whh_f = (const float*)d_in[5];
    const float* bih_f = (const float*)d_in[6];
    const float* bhh_f = (const float*)d_in[7];
    const float* Wih_b = (const float*)d_in[8];
    const float* Whh_b = (const float*)d_in[9];
    const float* bih_b = (const float*)d_in[10];
    const float* bhh_b = (const float*)d_in[11];
    const float* W_out = (const float*)d_in[12];
    const float* b_out = (const float*)d_in[13];

    char* ws = (char*)d_ws;
    float*  preT      = (float*)ws;                         // 2*128*512*4 = 512 KB
    __bf16* WhhB      = (__bf16*)(ws + 524288);             // 2*512*128*2 = 256 KB
    __bf16* Wpad      = (__bf16*)(ws + 524288 + 262144);    // 512*576*2   = 576 KB
    __bf16* char_feat = (__bf16*)(ws + 524288 + 262144 + 589824);  // 8192*256*2 = 4 MB

    prep_kernel<<<256 + (OUTD * KPAD + 2 * G4 * HID + 255) / 256, 256, 0, stream>>>(
        char_table, Wih_f, bih_f, bhh_f, Wih_b, bih_b, bhh_b,
        W_out, Whh_f, Whh_b, preT, Wpad, WhhB);
    lstm_kernel<<<dim3(N_WORDS / WBL, 2), 512, 0, stream>>>(char_ids, preT, WhhB, char_feat);
    out_kernel<<<N_WORDS / WB, 256, 0, stream>>>(word_ids, word_table, char_feat, Wpad, b_out,
                                                 (float*)d_out);
}

// Round 6
// 203.895 us; speedup vs baseline: 1.0900x; 1.0900x over previous
//
#include <hip/hip_runtime.h>
#include <hip/hip_bf16.h>

typedef __bf16 bf16x8 __attribute__((ext_vector_type(8)));
typedef float  f32x4  __attribute__((ext_vector_type(4)));
typedef int    i32x4  __attribute__((ext_vector_type(4)));

#define N_WORDS   8192
#define CHAR_LEN  16
#define WORD_DIM  300
#define CHAR_DIM  64
#define HID       128
#define G4        512      // 4*HID
#define INFO      556
#define KPAD      576      // 556 padded to 18*32
#define OUTD      512
#define WBL       32       // words per lstm block (2 M-tiles)
#define WBO       32       // words per out block
#define L2E       1.4426950408889634f

// sigmoid: rcp(1+exp2(-x*log2e)) ; saturates correctly
__device__ __forceinline__ float sig_(float x) {
    return __builtin_amdgcn_rcpf(1.0f + __builtin_amdgcn_exp2f(-L2E * x));
}
// tanh: 1 - 2*rcp(1+exp2(2x*log2e)) ; correct at +-inf
__device__ __forceinline__ float tanh_(float x) {
    return 1.0f - 2.0f * __builtin_amdgcn_rcpf(1.0f + __builtin_amdgcn_exp2f((2.0f * L2E) * x));
}

// K0 fused: blocks [0,256): preT ; blocks [256,...): Wpad + WhhB conversion
__global__ void prep_kernel(const float* __restrict__ char_table,
                            const float* __restrict__ Wih_f, const float* __restrict__ bih_f,
                            const float* __restrict__ bhh_f,
                            const float* __restrict__ Wih_b, const float* __restrict__ bih_b,
                            const float* __restrict__ bhh_b,
                            const float* __restrict__ W_out,
                            const float* __restrict__ Whh_f, const float* __restrict__ Whh_b,
                            float* __restrict__ preT,
                            __bf16* __restrict__ Wpad, __bf16* __restrict__ WhhB) {
    __shared__ float x[CHAR_DIM];
    if (blockIdx.x < 256) {
        const int dir = blockIdx.x & 1;
        const int cid = blockIdx.x >> 1;
        const float* Wih = dir ? Wih_b : Wih_f;
        const float* b1  = dir ? bih_b : bih_f;
        const float* b2  = dir ? bhh_b : bhh_f;
        if (threadIdx.x < CHAR_DIM) x[threadIdx.x] = char_table[cid * CHAR_DIM + threadIdx.x];
        __syncthreads();
        for (int g = threadIdx.x; g < G4; g += 256) {
            const f32x4* w4 = (const f32x4*)(Wih + g * CHAR_DIM);
            const f32x4* x4 = (const f32x4*)x;
            float s = b1[g] + b2[g];
            #pragma unroll
            for (int d = 0; d < CHAR_DIM / 4; ++d) {
                f32x4 wv = w4[d], xv = x4[d];
                s += wv[0]*xv[0] + wv[1]*xv[1] + wv[2]*xv[2] + wv[3]*xv[3];
            }
            int tt = g >> 7, j = g & (HID - 1);
            preT[(dir * 128 + cid) * G4 + j * 4 + tt] = s;
        }
    } else {
        int idx = (blockIdx.x - 256) * 256 + threadIdx.x;
        if (idx < OUTD * KPAD) {
            int row = idx / KPAD, col = idx - row * KPAD;
            Wpad[idx] = (col < INFO) ? (__bf16)W_out[row * INFO + col] : (__bf16)0.0f;
        } else {
            int j = idx - OUTD * KPAD;
            if (j < 2 * G4 * HID) {
                const float* src = (j < G4 * HID) ? Whh_f : Whh_b;
                int k = (j < G4 * HID) ? j : j - G4 * HID;
                WhhB[j] = (__bf16)src[k];
            }
        }
    }
}

// K2: persistent BiLSTM recurrence (unchanged from R5). Block: 32 words x 1 dir, 512 thr.
__global__ __launch_bounds__(512, 2) void lstm_kernel(
        const int*   __restrict__ char_ids,
        const float* __restrict__ preT,       // [2][128][128][4] fp32 gate-interleaved
        const __bf16* __restrict__ WhhB,      // [2][512][128] bf16
        __bf16* __restrict__ char_feat) {     // [8192][256] bf16
    const int dir = blockIdx.y;
    const int wb  = blockIdx.x * WBL;
    const __bf16* Whh = WhhB + dir * G4 * HID;
    const float* preD = preT + dir * 128 * G4;

    const int tid  = threadIdx.x;
    const int wave = tid >> 6;
    const int lane = tid & 63;
    const int col  = lane & 15;
    const int quad = lane >> 4;
    const int jbase = wave * 16;

    __shared__ __bf16 h_lds[2][WBL][136];
    __shared__ int    cidT[CHAR_LEN][WBL];

    {
        int w = tid >> 4, t = tid & 15;
        cidT[t][w] = char_ids[(wb + w) * CHAR_LEN + t] * (G4 * 4);
    }
    for (int i = tid; i < 2 * WBL * 136; i += 512) ((__bf16*)h_lds)[i] = (__bf16)0.0f;

    bf16x8 Bfrag[4][4];
    #pragma unroll
    for (int tt = 0; tt < 4; ++tt) {
        int row = tt * HID + jbase + col;
        #pragma unroll
        for (int ks = 0; ks < 4; ++ks)
            Bfrag[tt][ks] = *(const bf16x8*)(Whh + row * HID + ks * 32 + quad * 8);
    }

    const char* base_lane = (const char*)(preD + (jbase + col) * 4);

    float c[2][4] = {}, sumh[2][4] = {};

    __syncthreads();

    f32x4 nx[2][4];
    {
        const int tc0 = dir ? (CHAR_LEN - 1) : 0;
        #pragma unroll
        for (int mt = 0; mt < 2; ++mt) {
            i32x4 off = *(const i32x4*)(&cidT[tc0][mt * 16 + quad * 4]);
            #pragma unroll
            for (int r = 0; r < 4; ++r)
                nx[mt][r] = *(const f32x4*)(base_lane + off[r]);
        }
    }

    for (int t = 0; t < CHAR_LEN; ++t) {
        const __bf16 (*hc)[136] = h_lds[t & 1];
        __bf16 (*hn)[136] = h_lds[(t + 1) & 1];

        f32x4 acc[2][4];
        #pragma unroll
        for (int mt = 0; mt < 2; ++mt)
            #pragma unroll
            for (int tt = 0; tt < 4; ++tt)
                acc[mt][tt] = (f32x4){nx[mt][0][tt], nx[mt][1][tt], nx[mt][2][tt], nx[mt][3][tt]};

        {
            bf16x8 A0 = *(const bf16x8*)(&hc[col][quad * 8]);
            bf16x8 A1 = *(const bf16x8*)(&hc[16 + col][quad * 8]);
            #pragma unroll
            for (int tt = 0; tt < 4; ++tt) {
                acc[0][tt] = __builtin_amdgcn_mfma_f32_16x16x32_bf16(A0, Bfrag[tt][0], acc[0][tt], 0, 0, 0);
                acc[1][tt] = __builtin_amdgcn_mfma_f32_16x16x32_bf16(A1, Bfrag[tt][0], acc[1][tt], 0, 0, 0);
            }
        }

        if (t + 1 < CHAR_LEN) {
            const int tc = dir ? (CHAR_LEN - 2 - t) : (t + 1);
            #pragma unroll
            for (int mt = 0; mt < 2; ++mt) {
                i32x4 off = *(const i32x4*)(&cidT[tc][mt * 16 + quad * 4]);
                #pragma unroll
                for (int r = 0; r < 4; ++r)
                    nx[mt][r] = *(const f32x4*)(base_lane + off[r]);
            }
        }

        #pragma unroll
        for (int ks = 1; ks < 4; ++ks) {
            bf16x8 A0 = *(const bf16x8*)(&hc[col][ks * 32 + quad * 8]);
            bf16x8 A1 = *(const bf16x8*)(&hc[16 + col][ks * 32 + quad * 8]);
            #pragma unroll
            for (int tt = 0; tt < 4; ++tt) {
                acc[0][tt] = __builtin_amdgcn_mfma_f32_16x16x32_bf16(A0, Bfrag[tt][ks], acc[0][tt], 0, 0, 0);
                acc[1][tt] = __builtin_amdgcn_mfma_f32_16x16x32_bf16(A1, Bfrag[tt][ks], acc[1][tt], 0, 0, 0);
            }
        }

        #pragma unroll
        for (int mt = 0; mt < 2; ++mt)
            #pragma unroll
            for (int r = 0; r < 4; ++r) {
                float iv = sig_(acc[mt][0][r]);
                float fv = sig_(acc[mt][1][r]);
                float gv = tanh_(acc[mt][2][r]);
                float ov = sig_(acc[mt][3][r]);
                float cv = fv * c[mt][r] + iv * gv;
                c[mt][r] = cv;
                float hv = ov * tanh_(cv);
                sumh[mt][r] += hv;
                hn[mt * 16 + quad * 4 + r][jbase + col] = (__bf16)hv;
            }
        __syncthreads();
    }

    #pragma unroll
    for (int mt = 0; mt < 2; ++mt)
        #pragma unroll
        for (int r = 0; r < 4; ++r)
            char_feat[(wb + mt * 16 + quad * 4 + r) * 256 + dir * HID + jbase + col]
                = (__bf16)sumh[mt][r];
}

// K3 v2: 1024 thr (16 waves), M=32 words/block, wave owns M32 x N32 tile.
// Grid 256 = 1 block/CU -> 16 waves/CU hiding L2 B-load latency.
__global__ __launch_bounds__(1024, 4) void out_kernel(
        const int*   __restrict__ word_ids,
        const float* __restrict__ word_table,   // [50000][300] fp32
        const __bf16* __restrict__ char_feat,   // [8192][256] bf16
        const __bf16* __restrict__ Wpad,        // [512][576] bf16
        const float* __restrict__ b_out,        // [512] fp32
        float* __restrict__ out) {              // [8192][512] fp32
    const int wb  = blockIdx.x * WBO;
    const int tid = threadIdx.x;
    const int wave = tid >> 6, lane = tid & 63, col = lane & 15, quad = lane >> 4;
    const int nbase = wave * 32;   // 16 waves x 32 = 512 outputs

    __shared__ __bf16 feat[WBO][584];   // 1168B row stride, 16B aligned
    __shared__ int wid[WBO];
    if (tid < WBO) wid[tid] = word_ids[wb + tid];
    __syncthreads();
    // word part: 32 rows x 75 f32x4 chunks
    for (int idx = tid; idx < WBO * 75; idx += 1024) {
        int row = idx / 75, ch = idx - row * 75;
        f32x4 v = *(const f32x4*)(word_table + wid[row] * WORD_DIM + ch * 4);
        __bf16* d = &feat[row][ch * 4];
        d[0] = (__bf16)v[0]; d[1] = (__bf16)v[1]; d[2] = (__bf16)v[2]; d[3] = (__bf16)v[3];
    }
    // char part: 32 rows x 32 bf16x8 chunks = 1024 exactly
    {
        int row = tid >> 5, ch = tid & 31;
        bf16x8 v = *(const bf16x8*)(char_feat + (wb + row) * 256 + ch * 8);
        __bf16* d = &feat[row][WORD_DIM + ch * 8];
        #pragma unroll
        for (int e = 0; e < 8; ++e) d[e] = v[e];
    }
    // zero pad 556..583 : 32 x 28 = 896
    if (tid < WBO * 28) {
        int row = tid / 28, cc = tid - row * 28;
        feat[row][INFO + cc] = (__bf16)0.0f;
    }
    __syncthreads();

    f32x4 acc[2][2];   // [mt][nt]
    #pragma unroll
    for (int mt = 0; mt < 2; ++mt)
        #pragma unroll
        for (int nt = 0; nt < 2; ++nt) acc[mt][nt] = (f32x4){0.f, 0.f, 0.f, 0.f};

    const __bf16* Wp0 = Wpad + (nbase + col) * KPAD;
    const __bf16* Wp1 = Wpad + (nbase + 16 + col) * KPAD;

    #pragma unroll 2
    for (int kb = 0; kb < KPAD / 32; ++kb) {
        const int ko = kb * 32 + quad * 8;
        bf16x8 B0 = *(const bf16x8*)(Wp0 + ko);
        bf16x8 B1 = *(const bf16x8*)(Wp1 + ko);
        bf16x8 A0 = *(const bf16x8*)(&feat[col][ko]);
        bf16x8 A1 = *(const bf16x8*)(&feat[16 + col][ko]);
        acc[0][0] = __builtin_amdgcn_mfma_f32_16x16x32_bf16(A0, B0, acc[0][0], 0, 0, 0);
        acc[1][0] = __builtin_amdgcn_mfma_f32_16x16x32_bf16(A1, B0, acc[1][0], 0, 0, 0);
        acc[0][1] = __builtin_amdgcn_mfma_f32_16x16x32_bf16(A0, B1, acc[0][1], 0, 0, 0);
        acc[1][1] = __builtin_amdgcn_mfma_f32_16x16x32_bf16(A1, B1, acc[1][1], 0, 0, 0);
    }

    #pragma unroll
    for (int nt = 0; nt < 2; ++nt) {
        int n = nbase + nt * 16 + col;
        float bo = b_out[n];
        #pragma unroll
        for (int mt = 0; mt < 2; ++mt)
            #pragma unroll
            for (int r = 0; r < 4; ++r) {
                int word = wb + mt * 16 + quad * 4 + r;
                out[word * OUTD + n] = tanh_(acc[mt][nt][r] + bo);
            }
    }
}

extern "C" void kernel_launch(void* const* d_in, const int* in_sizes, int n_in,
                              void* d_out, int out_size, void* d_ws, size_t ws_size,
                              hipStream_t stream) {
    const int*   word_ids   = (const int*)d_in[0];
    const int*   char_ids   = (const int*)d_in[1];
    const float* word_table = (const float*)d_in[2];
    const float* char_table = (const float*)d_in[3];
    const float* Wih_f = (const float*)d_in[4];
    const float* Whh_f = (const float*)d_in[5];
    const float* bih_f = (const float*)d_in[6];
    const float* bhh_f = (const float*)d_in[7];
    const float* Wih_b = (const float*)d_in[8];
    const float* Whh_b = (const float*)d_in[9];
    const float* bih_b = (const float*)d_in[10];
    const float* bhh_b = (const float*)d_in[11];
    const float* W_out = (const float*)d_in[12];
    const float* b_out = (const float*)d_in[13];

    char* ws = (char*)d_ws;
    float*  preT      = (float*)ws;                         // 512 KB
    __bf16* WhhB      = (__bf16*)(ws + 524288);             // 256 KB
    __bf16* Wpad      = (__bf16*)(ws + 524288 + 262144);    // 576 KB
    __bf16* char_feat = (__bf16*)(ws + 524288 + 262144 + 589824);  // 4 MB

    prep_kernel<<<256 + (OUTD * KPAD + 2 * G4 * HID + 255) / 256, 256, 0, stream>>>(
        char_table, Wih_f, bih_f, bhh_f, Wih_b, bih_b, bhh_b,
        W_out, Whh_f, Whh_b, preT, Wpad, WhhB);
    lstm_kernel<<<dim3(N_WORDS / WBL, 2), 512, 0, stream>>>(char_ids, preT, WhhB, char_feat);
    out_kernel<<<N_WORDS / WBO, 1024, 0, stream>>>(word_ids, word_table, char_feat, Wpad, b_out,
                                                   (float*)d_out);
}